// Round 5
// baseline (6325.957 us; speedup 1.0000x reference)
//
#include <hip/hip_runtime.h>
#include <hip/hip_bf16.h>

typedef __attribute__((ext_vector_type(8))) _Float16 half8;
typedef __attribute__((ext_vector_type(4))) float floatx4;
typedef __attribute__((ext_vector_type(4))) unsigned uintx4;

#define NTS 512    // timesteps
#define NB  64     // batch
#define NI  256    // input dim
#define NH  512    // hidden
#define NWG 64     // 4 batch groups x 16 col groups
#define NTHR 512   // 8 waves

#define LOSCALE 4096.0f
#define LOINV   (1.0f / 4096.0f)

// fp32 -> (hi f16, lo f16 scaled by 2^12)
static __device__ __forceinline__ void split8s(const float* p, half8& hi, half8& lo) {
  float4 a = *(const float4*)p;
  float4 b = *(const float4*)(p + 4);
  float v[8] = {a.x, a.y, a.z, a.w, b.x, b.y, b.z, b.w};
#pragma unroll
  for (int i = 0; i < 8; ++i) {
    _Float16 h = (_Float16)v[i];
    hi[i] = h;
    lo[i] = (_Float16)((v[i] - (float)h) * LOSCALE);
  }
}

// pack one h cell with a 2-bit epoch stolen from the lo-plane mantissa LSBs:
// bits[15:0] = hi(f16); bits[31:18] = lo[15:2]; bits[17:16] = epoch.
static __device__ __forceinline__ unsigned pack_cell_e(float v, unsigned ep) {
  _Float16 h = (_Float16)v;
  _Float16 l = (_Float16)((v - (float)h) * LOSCALE);
  union { _Float16 f; unsigned short s; } uh, ul;
  uh.f = h; ul.f = l;
  unsigned lo = ((unsigned)ul.s & 0xFFFCu) | (ep & 3u);
  return (lo << 16) | (unsigned)uh.s;
}

// Coherent 16B load/store: sc0+sc1 = at the device coherence point.
static __device__ __forceinline__ uintx4 load_cx4(const unsigned* p) {
  uintx4 r;
  asm volatile("global_load_dwordx4 %0, %1, off sc0 sc1"
               : "=v"(r)
               : "v"((unsigned long long)p)
               : "memory");
  return r;
}
static __device__ __forceinline__ void store_cx4(unsigned* p, uintx4 v) {
  asm volatile("global_store_dwordx4 %0, %1, off sc0 sc1"
               :: "v"((unsigned long long)p), "v"(v)
               : "memory");
}

// Persistent LSTM v11: 64 WGs x 8 waves; WG = 16 batch rows x 32 hidden cols.
// Rationale (v10 post-mortem): the wait is coherent-fabric SERVICE time, not
// sync overhead. v11 halves stage transactions (131K vs 262K dwordx4/step),
// halves the straggler set (16 partners vs 32), and vectorizes publish 4x via
// an in-register 4x4 shfl transpose (8K dwordx4 stores vs 33K dword atomics).
// Epoch-in-data protocol unchanged (v9): parity double-buffer + 2-bit epoch in
// each cell; consumers retry stale quads; 0xAA poison = epoch 2 != E(0)=0.
__global__ void __launch_bounds__(NTHR, 2) lstm_persist_v11(
    const float* __restrict__ x,     // [512][64][256] fp32
    const float* __restrict__ h0,    // [64][512] fp32
    const float* __restrict__ c0,    // [64][512] fp32
    const float* __restrict__ w_ih,  // [2048][256] fp32
    const float* __restrict__ w_hh,  // [2048][512] fp32
    const float* __restrict__ b_ih,  // [2048] fp32
    const float* __restrict__ b_hh,  // [2048] fp32
    float* __restrict__ out,         // [512][64][512] ++ h_f ++ c_f (fp32)
    unsigned* __restrict__ hbuf)     // [2][64][512] packed u32 cells
{
  const int wg   = blockIdx.x;
  const int mh   = wg >> 4;        // batch quarter (group), 0..3
  const int ng   = wg & 15;        // hidden-col group (32 cols), 0..15
  const int b0   = mh * 16;
  const int j0   = ng * 32;
  const int tid  = threadIdx.x;
  const int wv   = tid >> 6;       // wave 0..7: owns cols j0+4*wv .. +3 (all 4 gates)
  const int lane = tid & 63;
  const int ln   = lane & 15;
  const int lq   = lane >> 4;
  const int gL   = ln >> 2;        // this lane's gate (B-frag row group)
  const int cL   = ln & 3;         // this lane's column within the wave's 4

  // LDS: whh lo-planes s=0..14 (s=15 lives in VGPR) + swizzled h staging tile.
  // hstage quads are XOR-swizzled (slot = qidx ^ (row&7)) on BOTH write and
  // read -> b128 8-lane/slot floor with zero padding. 122880+32768 = 155648 B.
  __shared__ uintx4    wlo[8][15][64];
  __shared__ unsigned  hstage[16][512];

  // ---- EMPIRICAL layout probe: local row of each acc slot (row = 4*lq + r) ----
  int row_l[4];
  {
    half8 ones, rowv;
#pragma unroll
    for (int i = 0; i < 8; ++i) { ones[i] = (_Float16)1.0f; rowv[i] = (_Float16)(float)ln; }
    floatx4 z = {0.f, 0.f, 0.f, 0.f};
    floatx4 p1 = __builtin_amdgcn_mfma_f32_16x16x32_f16(rowv, ones, z, 0, 0, 0);
#pragma unroll
    for (int r = 0; r < 4; ++r)
      row_l[r] = (int)(p1[r] * (1.0f / 32.0f) + 0.5f);
  }

  // ---- weights: hi-planes + wih-lo + whh-lo[15] -> VGPRs; whh-lo[0..14] -> LDS ----
  const int jg   = j0 + wv * 4 + cL;   // this lane's output column
  const int jb   = j0 + wv * 4;        // wave's column base
  const int grow = gL * NH + jg;       // row in w_ih/w_hh
  half8 whh_hi[16], wih_hi[8], wih_lo[8], whh_lo15;
  {
#pragma unroll
    for (int s = 0; s < 16; ++s) {
      half8 lo;
      split8s(w_hh + (size_t)grow * NH + 32 * s + 8 * lq, whh_hi[s], lo);
      if (s < 15) {
        union { half8 h; uintx4 u; } cv; cv.h = lo;
        wlo[wv][s][lane] = cv.u;
      } else {
        whh_lo15 = lo;
      }
    }
#pragma unroll
    for (int s = 0; s < 8; ++s)
      split8s(w_ih + (size_t)grow * NI + 32 * s + 8 * lq, wih_hi[s], wih_lo[s]);
  }

  // ---- per-lane cell state: 4 cells (b = b0+row_l[r], col = jg) ----
  const float bias_i = b_ih[jg]          + b_hh[jg];
  const float bias_f = b_ih[NH + jg]     + b_hh[NH + jg];
  const float bias_g = b_ih[2 * NH + jg] + b_hh[2 * NH + jg];
  const float bias_o = b_ih[3 * NH + jg] + b_hh[3 * NH + jg];

  int   bg_r[4];
  float c_s[4];
#pragma unroll
  for (int r = 0; r < 4; ++r) {
    bg_r[r] = b0 + row_l[r];
    c_s[r]  = c0[bg_r[r] * NH + jg];
  }
  // row this lane stores after the 4x4 transpose (select, not runtime-indexed)
  const int brow_st = b0 + ((cL == 0) ? row_l[0] : (cL == 1) ? row_l[1]
                           : (cL == 2) ? row_l[2] : row_l[3]);

  const int PAR = NB * NH;

  // ---- publish packed h0 (epoch 0) into parity 0 (one-time, scalar) ----
  if (gL == 0) {
#pragma unroll
    for (int r = 0; r < 4; ++r)
      __hip_atomic_store(&hbuf[bg_r[r] * NH + jg], pack_cell_e(h0[bg_r[r] * NH + jg], 0u),
                         __ATOMIC_RELAXED, __HIP_MEMORY_SCOPE_AGENT);
  }

  const int arow  = b0 + ln;          // A-fragment batch row
  const int srow  = tid & 15;         // staging: batch row
  const int qbase = (tid >> 4) * 4;   // staging: first quad index (4 quads/thread)

  for (int t = 0; t < NTS; ++t) {
    // ---- A) issue stage loads for h_t immediately (flight hides under x-part) ----
    const unsigned* hb = hbuf + (t & 1) * PAR + (b0 + srow) * NH + qbase * 4;
    uintx4 hv[4];
#pragma unroll
    for (int q = 0; q < 4; ++q) hv[q] = load_cx4(hb + 4 * q);

    // ---- B) x-part: h-independent ----
    floatx4 acc_x   = {0.f, 0.f, 0.f, 0.f};
    floatx4 accl_x1 = {0.f, 0.f, 0.f, 0.f};
    floatx4 accl_x2 = {0.f, 0.f, 0.f, 0.f};
#pragma unroll
    for (int s = 0; s < 8; ++s) {
      half8 xh, xl;
      split8s(x + ((size_t)t * NB + arow) * NI + 32 * s + 8 * lq, xh, xl);
      acc_x   = __builtin_amdgcn_mfma_f32_16x16x32_f16(xh, wih_hi[s], acc_x,   0, 0, 0);
      accl_x1 = __builtin_amdgcn_mfma_f32_16x16x32_f16(xl, wih_hi[s], accl_x1, 0, 0, 0);
      accl_x2 = __builtin_amdgcn_mfma_f32_16x16x32_f16(xh, wih_lo[s], accl_x2, 0, 0, 0);
    }

    // ---- C) barrier: prior-step hstage readers done ----
    __syncthreads();

    // ---- D) poll+stage: barrier-free per-wave epoch polling, 4 quads/thread ----
    {
      const unsigned em = (unsigned)((t >> 1) & 3) << 16;
      unsigned pend = 0xFu;
      for (;;) {
        asm volatile("s_waitcnt vmcnt(0)" ::: "memory");
#pragma unroll
        for (int q = 0; q < 4; ++q) {
          if (pend & (1u << q)) {
            uintx4 v = hv[q];
            unsigned bad = ((v[0] ^ em) | (v[1] ^ em) | (v[2] ^ em) | (v[3] ^ em))
                           & 0x00030000u;
            if (!bad) {
              const int slot = (qbase + q) ^ (srow & 7);
              *(uintx4*)&hstage[srow][slot << 2] = v;
              pend &= ~(1u << q);
            }
          }
        }
        if (__ballot(pend != 0u) == 0ull) break;
#pragma unroll
        for (int q = 0; q < 4; ++q)
          if (pend & (1u << q)) hv[q] = load_cx4(hb + 4 * q);
      }
    }
    __syncthreads();     // all stage writes visible to all waves

    // ---- E) h-part: gates += h_t*Whh^T; 6 independent 8-deep MFMA chains ----
    floatx4 acc_h  = {0.f, 0.f, 0.f, 0.f}, acc_h2  = {0.f, 0.f, 0.f, 0.f};
    floatx4 accl_a = {0.f, 0.f, 0.f, 0.f}, accl_a2 = {0.f, 0.f, 0.f, 0.f};
    floatx4 accl_b = {0.f, 0.f, 0.f, 0.f}, accl_b2 = {0.f, 0.f, 0.f, 0.f};
#pragma unroll
    for (int s = 0; s < 16; ++s) {
      const int q0 = 8 * s + 2 * lq;
      uintx4 hA = *(const uintx4*)&hstage[ln][(q0 ^ (ln & 7)) << 2];
      uintx4 hB = *(const uintx4*)&hstage[ln][((q0 + 1) ^ (ln & 7)) << 2];
      union { unsigned u[4]; half8 h; } Ah, Al;
      Ah.u[0] = __builtin_amdgcn_perm(hA[1], hA[0], 0x05040100u);
      Al.u[0] = __builtin_amdgcn_perm(hA[1], hA[0], 0x07060302u);
      Ah.u[1] = __builtin_amdgcn_perm(hA[3], hA[2], 0x05040100u);
      Al.u[1] = __builtin_amdgcn_perm(hA[3], hA[2], 0x07060302u);
      Ah.u[2] = __builtin_amdgcn_perm(hB[1], hB[0], 0x05040100u);
      Al.u[2] = __builtin_amdgcn_perm(hB[1], hB[0], 0x07060302u);
      Ah.u[3] = __builtin_amdgcn_perm(hB[3], hB[2], 0x05040100u);
      Al.u[3] = __builtin_amdgcn_perm(hB[3], hB[2], 0x07060302u);
      half8 wlh;
      if (s < 15) {
        union { uintx4 u; half8 h; } wl; wl.u = wlo[wv][s][lane];
        wlh = wl.h;
      } else {
        wlh = whh_lo15;
      }
      if (s < 8) {
        acc_h  = __builtin_amdgcn_mfma_f32_16x16x32_f16(Ah.h, whh_hi[s], acc_h,  0, 0, 0);
        accl_a = __builtin_amdgcn_mfma_f32_16x16x32_f16(Al.h, whh_hi[s], accl_a, 0, 0, 0);
        accl_b = __builtin_amdgcn_mfma_f32_16x16x32_f16(Ah.h, wlh,       accl_b, 0, 0, 0);
      } else {
        acc_h2  = __builtin_amdgcn_mfma_f32_16x16x32_f16(Ah.h, whh_hi[s], acc_h2,  0, 0, 0);
        accl_a2 = __builtin_amdgcn_mfma_f32_16x16x32_f16(Al.h, whh_hi[s], accl_a2, 0, 0, 0);
        accl_b2 = __builtin_amdgcn_mfma_f32_16x16x32_f16(Ah.h, wlh,       accl_b2, 0, 0, 0);
      }
    }

    // ---- F) pointwise LSTM cell: gather i/f/g/o across the 4 gate lane-groups ----
    const int par1 = ((t + 1) & 1) * PAR;
    const unsigned ep1 = (unsigned)(((t + 1) >> 1) & 3);
    float hn[4];
#pragma unroll
    for (int r = 0; r < 4; ++r) {
      float hi_s = acc_x[r] + acc_h[r] + acc_h2[r];
      float lo_s = accl_x1[r] + accl_x2[r] + accl_a[r] + accl_a2[r]
                 + accl_b[r] + accl_b2[r];
      float pre = hi_s + lo_s * LOINV;
      float pb = __shfl_xor(pre, 4);   // value from gate gL^1
      float pc = __shfl_xor(pre, 8);   // value from gate gL^2
      float pd = __shfl_xor(pb, 8);    // value from gate gL^3
      const bool g1 = (gL & 1), g2 = (gL & 2) != 0;
      float xi = g2 ? (g1 ? pd : pc) : (g1 ? pb : pre);
      float xf = g2 ? (g1 ? pc : pd) : (g1 ? pre : pb);
      float xg = g2 ? (g1 ? pb : pre) : (g1 ? pd : pc);
      float xo = g2 ? (g1 ? pre : pb) : (g1 ? pc : pd);
      xi += bias_i; xf += bias_f; xg += bias_g; xo += bias_o;
      float ig = 1.f / (1.f + __expf(-xi));
      float fg = 1.f / (1.f + __expf(-xf));
      float gg = 2.f / (1.f + __expf(-2.f * xg)) - 1.f;   // tanh
      float og = 1.f / (1.f + __expf(-xo));
      c_s[r] = fg * c_s[r] + ig * gg;
      float tc = 2.f / (1.f + __expf(-2.f * c_s[r])) - 1.f;  // tanh(c)
      hn[r] = og * tc;
    }

    if (t < NTS - 1) {
      // ---- G) 4x4 lane transpose (xor 1 then xor 2): lane p of each quad-group
      //      ends up with row bg_r[p], cols jb..jb+3 -> ONE dwordx4 publish ----
      const bool c0b = (lane & 1), c1b = (lane & 2) != 0;
      float a0 = __shfl_xor(hn[1], 1), a1 = __shfl_xor(hn[0], 1);
      float a2 = __shfl_xor(hn[3], 1), a3 = __shfl_xor(hn[2], 1);
      float v10 = c0b ? a0 : hn[0], v11 = c0b ? hn[1] : a1;
      float v12 = c0b ? a2 : hn[2], v13 = c0b ? hn[3] : a3;
      float b0v = __shfl_xor(v12, 2), b1v = __shfl_xor(v13, 2);
      float b2v = __shfl_xor(v10, 2), b3v = __shfl_xor(v11, 2);
      float T0 = c1b ? b0v : v10, T1 = c1b ? b1v : v11;
      float T2 = c1b ? v12 : b2v, T3 = c1b ? v13 : b3v;

      if (gL == 0) {
        uintx4 pk;
        pk[0] = pack_cell_e(T0, ep1);
        pk[1] = pack_cell_e(T1, ep1);
        pk[2] = pack_cell_e(T2, ep1);
        pk[3] = pack_cell_e(T3, ep1);
        store_cx4(&hbuf[par1 + brow_st * NH + jb], pk);     // publish FIRST
        floatx4 ov = {T0, T1, T2, T3};
        *(floatx4*)&out[((size_t)t * NB + brow_st) * NH + jb] = ov;
      }
    } else {
      if (gL == 0) {
        const size_t hf_off = (size_t)NTS * NB * NH;
#pragma unroll
        for (int r = 0; r < 4; ++r) {
          out[((size_t)t * NB + bg_r[r]) * NH + jg] = hn[r];
          out[hf_off + bg_r[r] * NH + jg] = hn[r];                          // h_f
          out[hf_off + (size_t)NB * NH + bg_r[r] * NH + jg] = c_s[r];       // c_f
        }
      }
    }
  }
}

extern "C" void kernel_launch(void* const* d_in, const int* in_sizes, int n_in,
                              void* d_out, int out_size, void* d_ws, size_t ws_size,
                              hipStream_t stream) {
  const float* x    = (const float*)d_in[0];
  const float* h0   = (const float*)d_in[1];
  const float* c0   = (const float*)d_in[2];
  const float* w_ih = (const float*)d_in[3];
  const float* w_hh = (const float*)d_in[4];
  const float* b_ih = (const float*)d_in[5];
  const float* b_hh = (const float*)d_in[6];
  float* out = (float*)d_out;
  unsigned* hbuf = (unsigned*)d_ws;   // 2*64*512 u32 = 256 KB

  // 0xAA poison decodes to epoch 2 != E(0)=0: no workspace init needed.
  hipLaunchKernelGGL(lstm_persist_v11, dim3(NWG), dim3(NTHR), 0, stream,
                     x, h0, c0, w_ih, w_hh, b_ih, b_hh, out, hbuf);
}